// Round 2
// baseline (539.764 us; speedup 1.0000x reference)
//
#include <hip/hip_runtime.h>
#include <stdint.h>

#define BB 16
#define HH 1024
#define II 512

// ---- output element offsets (f32 elements, concat in return order) ----
#define OFF_H    0L
#define OFF_C    16384L
#define OFF_EWIX 32768L
#define OFF_EWIH 8421376L
#define OFF_EBI  25198592L
#define OFF_EWFX 25214976L
#define OFF_EWFH 33603584L
#define OFF_EBF  50380800L
#define OFF_EWCX 50397184L
#define OFF_EWCH 58785792L
#define OFF_EBC  75563008L

typedef float f4 __attribute__((ext_vector_type(4)));

__device__ __forceinline__ void load8f(const float* __restrict__ p, float* o) {
    float4 a = *(const float4*)p;
    float4 b = *(const float4*)(p + 4);
    o[0] = a.x; o[1] = a.y; o[2] = a.z; o[3] = a.w;
    o[4] = b.x; o[5] = b.y; o[6] = b.z; o[7] = b.w;
}

// ---------------------------------------------------------------------------
// Kernel 1 (RESTRUCTURED): 4 waves per block, one GATE per wave.
//  - 16 accumulators/wave (was 64/thread in the 1-wave version -> spill risk)
//  - 4x the wave count (4096 waves = 16/CU) for latency hiding
//  - reduction: LDS transpose (16 wr + 16 rd per lane) + 2 shfl_xor levels
//    (was a serial 64-read LDS sum)
// Epilogue math is bit-identical to the verified version.
// ---------------------------------------------------------------------------
__global__ __launch_bounds__(256) void k_gates(
    const float* __restrict__ x,
    const float* __restrict__ w_ix, const float* __restrict__ w_ih, const float* __restrict__ b_i,
    const float* __restrict__ w_fx, const float* __restrict__ w_fh, const float* __restrict__ b_f,
    const float* __restrict__ w_ox, const float* __restrict__ w_oh, const float* __restrict__ b_o,
    const float* __restrict__ w_cx, const float* __restrict__ w_ch, const float* __restrict__ b_c,
    const float* __restrict__ h_last, const float* __restrict__ c_last,
    const float* __restrict__ e_b_i, const float* __restrict__ e_b_f, const float* __restrict__ e_b_c,
    float* __restrict__ out, float* __restrict__ ws)
{
    const int h    = blockIdx.x;
    const int wave = threadIdx.x >> 6;   // gate: 0=i 1=f 2=o 3=c
    const int lane = threadIdx.x & 63;

    const float* wx; const float* wh;
    switch (wave) {
        case 0:  wx = w_ix; wh = w_ih; break;
        case 1:  wx = w_fx; wh = w_fh; break;
        case 2:  wx = w_ox; wh = w_oh; break;
        default: wx = w_cx; wh = w_ch; break;
    }

    float acc[BB];
    #pragma unroll
    for (int b = 0; b < BB; b++) acc[b] = 0.f;

    // --- x segment: K = 512 = 64 lanes * 8 ---
    {
        const int k = lane * 8;
        float wv[8];
        load8f(wx + (size_t)h * II + k, wv);
        #pragma unroll
        for (int b = 0; b < BB; b++) {
            float xv[8];
            load8f(x + b * II + k, xv);
            #pragma unroll
            for (int e = 0; e < 8; e++) acc[b] += wv[e] * xv[e];
        }
    }
    // --- h segments: K = 1024 = 2 chunks of 512 ---
    #pragma unroll
    for (int c0 = 0; c0 < 2; c0++) {
        const int k = c0 * 512 + lane * 8;
        float wv[8];
        load8f(wh + (size_t)h * HH + k, wv);
        #pragma unroll
        for (int b = 0; b < BB; b++) {
            float hv[8];
            load8f(h_last + b * HH + k, hv);
            #pragma unroll
            for (int e = 0; e < 8; e++) acc[b] += wv[e] * hv[e];
        }
    }

    // --- cross-lane reduction (per wave, 16 values x 64 lanes) ---
    __shared__ float red[4][64][17];
    __shared__ float pre_s[4][16];
    #pragma unroll
    for (int b = 0; b < BB; b++) red[wave][lane][b] = acc[b];
    __syncthreads();

    const int q  = lane >> 4;       // quarter 0..3
    const int bb = lane & 15;       // batch
    float part = 0.f;
    #pragma unroll
    for (int i = 0; i < 16; i++) part += red[wave][q * 16 + i][bb];
    part += __shfl_xor(part, 16, 64);
    part += __shfl_xor(part, 32, 64);
    if (lane < 16) pre_s[wave][lane] = part;
    __syncthreads();

    if (threadIdx.x < BB) {
        const int b = threadIdx.x;
        const int idx = b * HH + h;
        const float pi = pre_s[0][b] + b_i[h];
        const float pf = pre_s[1][b] + b_f[h];
        const float po = pre_s[2][b] + b_o[h];
        const float pc = pre_s[3][b] + b_c[h];
        const float ig = 1.f / (1.f + __expf(-pi));
        const float fg = 1.f / (1.f + __expf(-pf));
        const float og = 1.f / (1.f + __expf(-po));
        const float chat = tanhf(pc);
        const float cl = c_last[idx];
        const float cnew = fg * cl + ig * chat;
        const float hnew = og * cnew;
        const float di = ig * (1.f - ig);
        const float df = fg * (1.f - fg);
        const float dch = 1.f - chat * chat;
        const float ai = di * chat;
        const float af = df * cl;
        const float ac = dch * ig;

        out[OFF_H   + idx] = hnew;
        out[OFF_C   + idx] = cnew;
        out[OFF_EBI + idx] = e_b_i[idx] * fg + ai;
        out[OFF_EBF + idx] = e_b_f[idx] * fg + af;
        out[OFF_EBC + idx] = e_b_c[idx] * fg + ac;

        ws[idx]          = fg;
        ws[16384 + idx]  = ai;
        ws[32768 + idx]  = af;
        ws[49152 + idx]  = ac;
    }
}

// ---------------------------------------------------------------------------
// Kernel 2: six streaming trace updates, flat 1-D grid, uniform work.
//   new_e[b,h,j] = e[b,h,j]*f[b,h] + a[b,h]*src[b,j]
// Block layout: [ih:4096][fh:4096][ch:4096][ix:2048][fx:2048][cx:2048]
// Each block: 1024 float4 tile; each thread 4 float4 slots (lane-dense,
// perfect coalescing). All 8 vmem loads issued before any compute/store.
// NT on the 604 MB e/out streams only; x/h_last/ws stay L2-cached.
// ---------------------------------------------------------------------------
__global__ __launch_bounds__(256) void k_trace(
    const float* __restrict__ x, const float* __restrict__ h_last,
    const float* __restrict__ e_ix, const float* __restrict__ e_ih,
    const float* __restrict__ e_fx, const float* __restrict__ e_fh,
    const float* __restrict__ e_cx, const float* __restrict__ e_ch,
    const float* __restrict__ ws, float* __restrict__ out)
{
    const int bid = (int)blockIdx.x;
    int t, tile, is_h;
    if (bid < 12288) { t = bid >> 12; tile = bid & 4095; is_h = 1; }
    else { const int r = bid - 12288; t = 3 + (r >> 11); tile = r & 2047; is_h = 0; }
    const int qrl = 7 + is_h;                 // log2(float4 per row): 128 or 256

    const float* e_in; long ooff;
    switch (t) {
        case 0:  e_in = e_ih; ooff = OFF_EWIH; break;
        case 1:  e_in = e_fh; ooff = OFF_EWFH; break;
        case 2:  e_in = e_ch; ooff = OFF_EWCH; break;
        case 3:  e_in = e_ix; ooff = OFF_EWIX; break;
        case 4:  e_in = e_fx; ooff = OFF_EWFX; break;
        default: e_in = e_cx; ooff = OFF_EWCX; break;
    }
    const float* src = is_h ? h_last : x;
    const int a_sel = (t < 3) ? t : (t - 3);  // 0:a_i 1:a_f 2:a_c
    const int a_base = (a_sel + 1) << 14;

    const f4* e4 = (const f4*)e_in;
    const f4* s4 = (const f4*)src;
    f4* o4 = (f4*)(out + ooff);

    const int base = (tile << 10) + (int)threadIdx.x;

    f4 ev[4], sv[4];
    float fl[4], aa[4];
    int q[4];
    #pragma unroll
    for (int u = 0; u < 4; ++u) {
        q[u] = base + (u << 8);
        const int row = q[u] >> qrl;              // b*1024 + h
        const int jq  = q[u] & ((1 << qrl) - 1);  // f4 col within row
        const int b   = row >> 10;
        ev[u] = __builtin_nontemporal_load(e4 + q[u]);
        sv[u] = s4[(b << qrl) + jq];
        fl[u] = ws[row];
        aa[u] = ws[a_base + row];
    }
    #pragma unroll
    for (int u = 0; u < 4; ++u) {
        f4 r;
        r[0] = ev[u][0] * fl[u] + aa[u] * sv[u][0];
        r[1] = ev[u][1] * fl[u] + aa[u] * sv[u][1];
        r[2] = ev[u][2] * fl[u] + aa[u] * sv[u][2];
        r[3] = ev[u][3] * fl[u] + aa[u] * sv[u][3];
        __builtin_nontemporal_store(r, o4 + q[u]);
    }
}

extern "C" void kernel_launch(void* const* d_in, const int* in_sizes, int n_in,
                              void* d_out, int out_size, void* d_ws, size_t ws_size,
                              hipStream_t stream) {
    const float* x      = (const float*)d_in[0];
    const float* w_ix   = (const float*)d_in[1];
    const float* w_ih   = (const float*)d_in[2];
    const float* b_i    = (const float*)d_in[3];
    const float* w_fx   = (const float*)d_in[4];
    const float* w_fh   = (const float*)d_in[5];
    const float* b_f    = (const float*)d_in[6];
    const float* w_ox   = (const float*)d_in[7];
    const float* w_oh   = (const float*)d_in[8];
    const float* b_o    = (const float*)d_in[9];
    const float* w_cx   = (const float*)d_in[10];
    const float* w_ch   = (const float*)d_in[11];
    const float* b_c    = (const float*)d_in[12];
    const float* h_last = (const float*)d_in[13];
    const float* c_last = (const float*)d_in[14];
    const float* e_ix   = (const float*)d_in[15];
    const float* e_ih   = (const float*)d_in[16];
    const float* e_b_i  = (const float*)d_in[17];
    const float* e_fx   = (const float*)d_in[18];
    const float* e_fh   = (const float*)d_in[19];
    const float* e_b_f  = (const float*)d_in[20];
    const float* e_cx   = (const float*)d_in[21];
    const float* e_ch   = (const float*)d_in[22];
    const float* e_b_c  = (const float*)d_in[23];
    float* out = (float*)d_out;
    float* ws  = (float*)d_ws;

    k_gates<<<dim3(HH), dim3(256), 0, stream>>>(
        x, w_ix, w_ih, b_i, w_fx, w_fh, b_f, w_ox, w_oh, b_o, w_cx, w_ch, b_c,
        h_last, c_last, e_b_i, e_b_f, e_b_c, out, ws);

    k_trace<<<dim3(18432), dim3(256), 0, stream>>>(
        x, h_last, e_ix, e_ih, e_fx, e_fh, e_cx, e_ch, ws, out);
}